// Round 1
// baseline (254.669 us; speedup 1.0000x reference)
//
#include <hip/hip_runtime.h>

#define SIZE 1024
#define MM 10
#define NTERMS 10
#define RPB 8          // batch rows resident per block
#define NTHREADS 256

__device__ __forceinline__ float4 ldq(const float* p) { return *(const float4*)p; }

// a0..a3 live in the enclosing scope
#define FMA4(W, v0, v1, v2, v3)                                      \
    a0 = fmaf((W)[0], (v0), a0); a1 = fmaf((W)[1], (v1), a1);        \
    a2 = fmaf((W)[2], (v2), a2); a3 = fmaf((W)[3], (v3), a3);

// ---------------------------------------------------------------------------
// Hybrid kernel: near taps (d<=64) from LDS, far taps (d=128,256,512) from
// global (L1/L2 — block-private 32KB row set, same-CU coherent across
// __syncthreads). Rows ping-pong between gA(=ws) and gB(=out) each term;
// parity chosen so term 9 writes gB == out directly.
// FMA accumulation order is IDENTICAL to butterfly_fused (bitwise-same result).
// ---------------------------------------------------------------------------
__global__ __launch_bounds__(NTHREADS, 2)
void butterfly_hybrid(const float* __restrict__ x,
                      const float* __restrict__ diag,
                      const float* __restrict__ subpad,
                      const float* __restrict__ suppad,
                      const float* __restrict__ logit,
                      float* __restrict__ gA,    // ws : written at t=0,2,4,6,8
                      float* __restrict__ gB)    // out: written at t=1,3,5,7,9
{
    __shared__ float buf[2][RPB][SIZE];   // 64 KB -> 2 blocks/CU

    const int tid = threadIdx.x;
    const int s0  = tid * 4;
    const long rowbase = (long)blockIdx.x * RPB;

    #pragma unroll
    for (int r = 0; r < RPB; ++r) {
        *(float4*)&buf[0][r][s0] = ldq(x + (rowbase + r) * SIZE + s0);
    }
    __syncthreads();

    int cur = 0;
    for (int t = 0; t < NTERMS; ++t) {
        const int i = NTERMS - 1 - t;     // reference applies prob[9] first

        // ---- softmax over logit[i][:] ----
        float lg[MM];
        float mx = -3.4e38f;
        #pragma unroll
        for (int j = 0; j < MM; ++j) { lg[j] = logit[i * MM + j]; mx = fmaxf(mx, lg[j]); }
        float ssum = 0.f;
        #pragma unroll
        for (int j = 0; j < MM; ++j) { lg[j] = __expf(lg[j] - mx); ssum += lg[j]; }
        const float inv = 1.0f / ssum;

        // ---- prob-weighted coefficients for this thread's quad ----
        float D[4] = {0.f, 0.f, 0.f, 0.f};
        float Wsb[MM][4], Wsp[MM][4];
        #pragma unroll
        for (int j = 0; j < MM; ++j) {
            const float pj = lg[j] * inv;
            const float4 dg = ldq(diag   + j * SIZE + s0);
            const float4 sb = ldq(subpad + j * SIZE + s0);
            const float4 sp = ldq(suppad + j * SIZE + s0);
            D[0] = fmaf(pj, dg.x, D[0]); D[1] = fmaf(pj, dg.y, D[1]);
            D[2] = fmaf(pj, dg.z, D[2]); D[3] = fmaf(pj, dg.w, D[3]);
            Wsb[j][0] = pj * sb.x; Wsb[j][1] = pj * sb.y;
            Wsb[j][2] = pj * sb.z; Wsb[j][3] = pj * sb.w;
            Wsp[j][0] = pj * sp.x; Wsp[j][1] = pj * sp.y;
            Wsp[j][2] = pj * sp.z; Wsp[j][3] = pj * sp.w;
        }

        // term t reads far taps from gin, writes updated rows to gout
        const float* gin  = (t == 0) ? x : (const float*)((t & 1) ? gA : gB);
        float*       gout = (t & 1) ? gB : gA;
        const float* ginb  = gin  + rowbase * SIZE;
        float*       goutb = gout + rowbase * SIZE;

        for (int r = 0; r < RPB; ++r) {
            const float* row  = &buf[cur][r][0];
            float*       orow = &buf[cur ^ 1][r][0];
            const float* grow = ginb + r * SIZE;

            // ---- far taps via global (vmem pipe, L1/L2-resident) ----
            // j=0,1,2 -> d=512,256,128. Clamped addresses pair with all-zero coefs.
            const float4 f0m = ldq(grow + (s0 >= 512        ? s0 - 512 : 0));
            const float4 f0p = ldq(grow + (s0 + 512 <= 1020 ? s0 + 512 : 1020));
            const float4 f1m = ldq(grow + (s0 >= 256        ? s0 - 256 : 0));
            const float4 f1p = ldq(grow + (s0 + 256 <= 1020 ? s0 + 256 : 1020));
            const float4 f2m = ldq(grow + (s0 >= 128        ? s0 - 128 : 0));
            const float4 f2p = ldq(grow + (s0 + 128 <= 1020 ? s0 + 128 : 1020));

            const float4 xo = ldq(row + s0);
            float a0 = D[0] * xo.x, a1 = D[1] * xo.y,
                  a2 = D[2] * xo.z, a3 = D[3] * xo.w;

            const float4 xl = ldq(row + (s0 >= 4          ? s0 - 4 : 0));
            const float4 xr = ldq(row + (s0 + 4 <= 1020   ? s0 + 4 : 1020));

            // j=9, d=1
            FMA4(Wsb[9], xl.w, xo.x, xo.y, xo.z)
            FMA4(Wsp[9], xo.y, xo.z, xo.w, xr.x)
            // j=8, d=2
            FMA4(Wsb[8], xl.z, xl.w, xo.x, xo.y)
            FMA4(Wsp[8], xo.z, xo.w, xr.x, xr.y)
            // j=7, d=4
            FMA4(Wsb[7], xl.x, xl.y, xl.z, xl.w)
            FMA4(Wsp[7], xr.x, xr.y, xr.z, xr.w)
            // j=0..2, d=512,256,128 (far, from global-loaded registers)
            FMA4(Wsb[0], f0m.x, f0m.y, f0m.z, f0m.w)
            FMA4(Wsp[0], f0p.x, f0p.y, f0p.z, f0p.w)
            FMA4(Wsb[1], f1m.x, f1m.y, f1m.z, f1m.w)
            FMA4(Wsp[1], f1p.x, f1p.y, f1p.z, f1p.w)
            FMA4(Wsb[2], f2m.x, f2m.y, f2m.z, f2m.w)
            FMA4(Wsp[2], f2p.x, f2p.y, f2p.z, f2p.w)
            // j=3..6, d=64,32,16,8 (near, LDS)
            #pragma unroll
            for (int j = 3; j <= 6; ++j) {
                const int d = 512 >> j;
                const float4 xm = ldq(row + (s0 >= d        ? s0 - d : 0));
                const float4 xp = ldq(row + (s0 + d <= 1020 ? s0 + d : 1020));
                FMA4(Wsb[j], xm.x, xm.y, xm.z, xm.w)
                FMA4(Wsp[j], xp.x, xp.y, xp.z, xp.w)
            }

            const float4 res = make_float4(a0, a1, a2, a3);
            *(float4*)(orow + s0) = res;                 // near-tap source, next term
            *(float4*)(goutb + r * SIZE + s0) = res;     // far-tap source, next term
        }
        __syncthreads();   // drains vmcnt+lgkmcnt: both buf[cur^1] and gout visible
        cur ^= 1;
    }
    // t=9 wrote gB == out for every row/quad: no epilogue needed.
}

// ---------------------------------------------------------------------------
// Fallback: the proven pure-LDS kernel (used if ws is too small to ping-pong).
// ---------------------------------------------------------------------------
__global__ __launch_bounds__(NTHREADS, 2)
void butterfly_fused(const float* __restrict__ x,
                     const float* __restrict__ diag,
                     const float* __restrict__ subpad,
                     const float* __restrict__ suppad,
                     const float* __restrict__ logit,
                     float* __restrict__ out)
{
    __shared__ float buf[2][RPB][SIZE];

    const int tid = threadIdx.x;
    const int s0  = tid * 4;
    const long rowbase = (long)blockIdx.x * RPB;

    #pragma unroll
    for (int r = 0; r < RPB; ++r) {
        *(float4*)&buf[0][r][s0] = ldq(x + (rowbase + r) * SIZE + s0);
    }
    __syncthreads();

    int cur = 0;
    for (int t = 0; t < NTERMS; ++t) {
        const int i = NTERMS - 1 - t;

        float lg[MM];
        float mx = -3.4e38f;
        #pragma unroll
        for (int j = 0; j < MM; ++j) { lg[j] = logit[i * MM + j]; mx = fmaxf(mx, lg[j]); }
        float ssum = 0.f;
        #pragma unroll
        for (int j = 0; j < MM; ++j) { lg[j] = __expf(lg[j] - mx); ssum += lg[j]; }
        const float inv = 1.0f / ssum;

        float D[4] = {0.f, 0.f, 0.f, 0.f};
        float Wsb[MM][4], Wsp[MM][4];
        #pragma unroll
        for (int j = 0; j < MM; ++j) {
            const float pj = lg[j] * inv;
            const float4 dg = ldq(diag   + j * SIZE + s0);
            const float4 sb = ldq(subpad + j * SIZE + s0);
            const float4 sp = ldq(suppad + j * SIZE + s0);
            D[0] = fmaf(pj, dg.x, D[0]); D[1] = fmaf(pj, dg.y, D[1]);
            D[2] = fmaf(pj, dg.z, D[2]); D[3] = fmaf(pj, dg.w, D[3]);
            Wsb[j][0] = pj * sb.x; Wsb[j][1] = pj * sb.y;
            Wsb[j][2] = pj * sb.z; Wsb[j][3] = pj * sb.w;
            Wsp[j][0] = pj * sp.x; Wsp[j][1] = pj * sp.y;
            Wsp[j][2] = pj * sp.z; Wsp[j][3] = pj * sp.w;
        }

        for (int r = 0; r < RPB; ++r) {
            const float* row  = &buf[cur][r][0];
            float*       orow = &buf[cur ^ 1][r][0];

            const float4 xo = ldq(row + s0);
            float a0 = D[0] * xo.x, a1 = D[1] * xo.y,
                  a2 = D[2] * xo.z, a3 = D[3] * xo.w;

            const float4 xl = ldq(row + (s0 >= 4          ? s0 - 4 : 0));
            const float4 xr = ldq(row + (s0 + 4 <= 1020   ? s0 + 4 : 1020));

            FMA4(Wsb[9], xl.w, xo.x, xo.y, xo.z)
            FMA4(Wsp[9], xo.y, xo.z, xo.w, xr.x)
            FMA4(Wsb[8], xl.z, xl.w, xo.x, xo.y)
            FMA4(Wsp[8], xo.z, xo.w, xr.x, xr.y)
            FMA4(Wsb[7], xl.x, xl.y, xl.z, xl.w)
            FMA4(Wsp[7], xr.x, xr.y, xr.z, xr.w)
            #pragma unroll
            for (int j = 0; j <= 6; ++j) {
                const int d = 512 >> j;
                const float4 xm = ldq(row + (s0 >= d        ? s0 - d : 0));
                const float4 xp = ldq(row + (s0 + d <= 1020 ? s0 + d : 1020));
                FMA4(Wsb[j], xm.x, xm.y, xm.z, xm.w)
                FMA4(Wsp[j], xp.x, xp.y, xp.z, xp.w)
            }

            *(float4*)(orow + s0) = make_float4(a0, a1, a2, a3);
        }
        __syncthreads();
        cur ^= 1;
    }

    #pragma unroll
    for (int r = 0; r < RPB; ++r) {
        *(float4*)(out + (rowbase + r) * SIZE + s0) = ldq(&buf[cur][r][s0]);
    }
}

extern "C" void kernel_launch(void* const* d_in, const int* in_sizes, int n_in,
                              void* d_out, int out_size, void* d_ws, size_t ws_size,
                              hipStream_t stream) {
    const float* x      = (const float*)d_in[0];
    const float* diag   = (const float*)d_in[1];
    const float* subpad = (const float*)d_in[2];
    const float* suppad = (const float*)d_in[3];
    const float* logit  = (const float*)d_in[4];
    float* outp = (float*)d_out;

    const int batch = in_sizes[0] / SIZE;      // 8192
    const int nblocks = batch / RPB;           // 1024
    const size_t need = (size_t)batch * SIZE * sizeof(float);   // 32 MiB ping-pong buffer

    if (ws_size >= need && d_ws != nullptr) {
        butterfly_hybrid<<<dim3(nblocks), dim3(NTHREADS), 0, stream>>>(
            x, diag, subpad, suppad, logit, (float*)d_ws, outp);
    } else {
        butterfly_fused<<<dim3(nblocks), dim3(NTHREADS), 0, stream>>>(
            x, diag, subpad, suppad, logit, outp);
    }
}